// Round 26
// baseline (131.767 us; speedup 1.0000x reference)
//
#include <hip/hip_runtime.h>
#include <stdint.h>
#include <math.h>

#define NEGV -1000000000.0f

constexpr int NG   = 256;   // graphs
constexpr int NL   = 32;    // nodes per graph == L == steps
constexpr int NT   = 1024;  // threads per block
constexpr int NTOT = 8192;  // total nodes
constexpr int S3   = 33;    // f32 stride for per-lane-row arrays
constexpr int SH   = 20;    // h2 stride (40 f16, 80B rows, 16B-aligned)

typedef _Float16 f16;
typedef __attribute__((ext_vector_type(2))) _Float16 h2;
typedef __attribute__((ext_vector_type(8))) _Float16 h8;
typedef __attribute__((ext_vector_type(8))) _Float16 f16x8;
typedef __attribute__((ext_vector_type(4))) float f32x4;

union H8 { h8 v; h2 e[4]; };

__device__ __forceinline__ h2 mkh2(float a, float b) {   // RNE pack
  return (h2){(_Float16)a, (_Float16)b};
}

__device__ __forceinline__ H8 ld8(const h2* p) {
  H8 r; r.v = *(const h8*)__builtin_assume_aligned(p, 16); return r;
}

__device__ __forceinline__ float lrelu(float v) { return fmaxf(v, 0.01f * v); }

__device__ __forceinline__ void lds_barrier() {
  asm volatile("s_waitcnt lgkmcnt(0)" ::: "memory");
  __builtin_amdgcn_sched_barrier(0);
  __builtin_amdgcn_s_barrier();
  __builtin_amdgcn_sched_barrier(0);
}

__device__ __forceinline__ float fsigmoid(float x) {
  return __builtin_amdgcn_rcpf(1.f + __expf(-x));
}
__device__ __forceinline__ float ftanh(float x) {
  x = fminf(fmaxf(x, -15.f), 15.f);
  float e = __expf(2.f * x);
  return (e - 1.f) * __builtin_amdgcn_rcpf(e + 1.f);
}

union F8 { h2 h[4]; f16x8 v; };

// load 8 consecutive f32 of row `row` of a 32-wide matrix as one f16 fragment
__device__ __forceinline__ void loadWrow(const float* __restrict__ W, int row, int kslc, F8& f) {
  const float4 lo = *(const float4*)&W[row * 32 + kslc];
  const float4 hi = *(const float4*)&W[row * 32 + kslc + 4];
  f.h[0] = mkh2(lo.x, lo.y); f.h[1] = mkh2(lo.z, lo.w);
  f.h[2] = mkh2(hi.x, hi.y); f.h[3] = mkh2(hi.z, hi.w);
}
// same for a 64-wide matrix (W_u)
__device__ __forceinline__ void loadWrow64(const float* __restrict__ W, int row, int kslc, F8& f) {
  const float4 lo = *(const float4*)&W[row * 64 + kslc];
  const float4 hi = *(const float4*)&W[row * 64 + kslc + 4];
  f.h[0] = mkh2(lo.x, lo.y); f.h[1] = mkh2(lo.z, lo.w);
  f.h[2] = mkh2(hi.x, hi.y); f.h[3] = mkh2(hi.z, hi.w);
}
// arbitrary-stride matrix — rows not 16B-aligned, scalar loads (init-only)
__device__ __forceinline__ void loadWrowS(const float* __restrict__ W, int row, int stride, int col0, F8& f) {
  #pragma unroll
  for (int q = 0; q < 4; ++q)
    f.h[q] = mkh2(W[row * stride + col0 + 2 * q], W[row * stride + col0 + 2 * q + 1]);
}

__global__ __launch_bounds__(NT, 4) void prims_fused(
    const float* __restrict__ x, const float* __restrict__ edge_attr,
    const float* __restrict__ W_enc, const float* __restrict__ W_m1,
    const float* __restrict__ W_m2, const float* __restrict__ W_u,
    const float* __restrict__ W_ih, const float* __restrict__ W_hh,
    const float* __restrict__ W_mst, const float* __restrict__ W_p1,
    const float* __restrict__ W_p2, float* __restrict__ out)
{
  // ping-pong hidden state (f16, stride SH=20 h2)
  __shared__ __align__(16) h2 sha[NL * SH];
  __shared__ __align__(16) h2 shb[NL * SH];
  __shared__ __align__(16) h2 senc16[NL * SH];   // enc
  __shared__ __align__(16) h2 sA16[NL * SH];     // msg dst-part; then u
  __shared__ __align__(16) h2 sB16[NL * SH];     // msg src-part
  __shared__ __align__(16) h2 saggr16[NL * SH];  // segment max
  __shared__ h2 swea16[16];                      // W_m1[:,64] pairs
  // f32 oddments
  __shared__ float sea[NL * S3];   // sea[j*S3 + i] = ea(src i, dst j)
  __shared__ float smst_e[2 * NL]; // mst enc-part per (nj, row)
  __shared__ float smst_h[2 * NL]; // mst h-part per (nj, row)
  __shared__ float sprev[NL];      // prev vector (for enc-MFMA correction)
  __shared__ float sWmst[2 * NL];
  __shared__ float swp1e[NL];      // W_p1[:,64]
  __shared__ float sC1[NL * S3];   // final predictor src-part
  __shared__ float sC2[NL * S3];   // final predictor dst-part

  const int t    = threadIdx.x;
  const int g    = blockIdx.x;
  const int p    = t >> 5;   // node row
  const int k    = t & 31;   // feature col
  const int w    = t >> 6;   // wave id (16)
  const int lane = t & 63;
  const int l32  = lane & 31;
  const int m16  = lane & 15;
  const int c0   = (lane >> 4) * 8;   // MFMA k-chunk base (f16 elems)
  const int cp0  = (lane >> 4) * 4;   // same in half2 units

  // ---- W_m2^T B-fragments (f16, resident in registers) ----
  F8 bf0, bf1;
  #pragma unroll
  for (int q = 0; q < 4; ++q) {
    bf0.h[q] = mkh2(W_m2[m16 * 32 + c0 + 2 * q],        W_m2[m16 * 32 + c0 + 2 * q + 1]);
    bf1.h[q] = mkh2(W_m2[(16 + m16) * 32 + c0 + 2 * q], W_m2[(16 + m16) * 32 + c0 + 2 * q + 1]);
  }

  // ---- per-wave GRU gate B-fragments (waves 0..3: one 16x16 tile, all 6 GEMMs) ----
  F8 gfRi, gfRh, gfZi, gfZh, gfNi, gfNh;
  if (w < 4) {
    const int nj = w & 1;
    const int wrow = nj * 16 + m16;   // weight row = output feature
    loadWrow(W_ih, wrow,      c0, gfRi); loadWrow(W_hh, wrow,      c0, gfRh);
    loadWrow(W_ih, 32 + wrow, c0, gfZi); loadWrow(W_hh, 32 + wrow, c0, gfZh);
    loadWrow(W_ih, 64 + wrow, c0, gfNi); loadWrow(W_hh, 64 + wrow, c0, gfNh);
  }

  // ---- per-wave u-phase + enc-phase B-fragments (waves 4..7) ----
  F8 ufE, ufG, efW;
  float w0col = 0.f, wmstE = 0.f;
  if (w >= 4 && w < 8) {
    const int q = w - 4;
    const int nj = q & 1;
    const int wrow = nj * 16 + m16;
    loadWrow64(W_u, wrow, c0,      ufE);        // K-cols  0..31 (enc part)
    loadWrow64(W_u, wrow, 32 + c0, ufG);        // K-cols 32..63 (aggr part)
    loadWrowS(W_enc, wrow, 33, 1 + c0, efW);    // W_enc[:,1:33] rows
    w0col = W_enc[wrow * 33];                   // W_enc[:,0] (prev term)
    wmstE = W_mst[wrow];                        // mst enc coefficient
  }

  // ---- per-wave A/B-phase B-fragments (waves 8..15: one 16x16 tile each) ----
  F8 mfW;   // W_m1 rows, cols 0..31 (A) or 32..63 (B)
  if (w >= 8) {
    const int q = (w - 8) & 3;
    const int nj = q & 1;
    const int wrow = nj * 16 + m16;
    const int colbase = (w < 12) ? 0 : 32;
    loadWrowS(W_m1, wrow, 65, colbase + c0, mfW);
  }

  // ---- one-time staging ----
  if (t < 16) swea16[t] = mkh2(W_m1[(2 * t) * 65 + 64], W_m1[(2 * t + 1) * 65 + 64]);
  if (t < NL) { swp1e[t] = W_p1[t * 65 + 64]; sprev[t] = x[(size_t)(g * NL + t) * 32]; }
  if (t < 2 * NL) sWmst[t] = W_mst[t];
  {
    int i = t >> 5, j = t & 31;           // edge t = i*32+j (src i, dst j)
    sea[j * S3 + i] = edge_attr[g * 1024 + t];
  }
  for (int idx = t; idx < NL * SH; idx += NT) sha[idx] = (h2){(_Float16)0.f, (_Float16)0.f};

  float prev_lane = x[(size_t)(g * NL + l32) * 32];  // prev[l32], for argmax (waves 4..7)

  __syncthreads();

  // hoisted static edge-phase operands
  h2 wv16[4];
  #pragma unroll
  for (int q = 0; q < 4; ++q) wv16[q] = swea16[cp0 + q];
  const int j0 = 2 * w, j1 = 2 * w + 1;
  h2 ea00, ea01, ea10, ea11;
  {
    f16 e;
    e = (f16)sea[j0 * S3 + m16];      ea00 = (h2){e, e};
    e = (f16)sea[j0 * S3 + 16 + m16]; ea01 = (h2){e, e};
    e = (f16)sea[j1 * S3 + m16];      ea10 = (h2){e, e};
    e = (f16)sea[j1 * S3 + 16 + m16]; ea11 = (h2){e, e};
  }
  const h2 h001 = {(_Float16)0.01f, (_Float16)0.01f};

  // ---- 32 steps ----
  for (int s = 0; s < 32; ++s) {
    h2* hsrc = (s & 1) ? shb : sha;
    h2* hdst = (s & 1) ? sha : shb;

    // NEG-fill: waves 8..15 only (idle during enc anyway); 4 float4/thread
    if (w >= 8) {
      const f32x4 nv = {NEGV, NEGV, NEGV, NEGV};
      const int tb = t - 512;               // 0..511
      #pragma unroll
      for (int q = 0; q < 4; ++q) {
        int idx = s * 2048 + tb * 4 + q;    // 0 .. 65535 over 32 steps
        int row = idx >> 11;                // 2048 float4 per row
        int c4  = idx & 2047;
        if ((c4 >> 3) != g) {
          f32x4* dptr = reinterpret_cast<f32x4*>(out + (size_t)(g * NL + row) * NTOT) + c4;
          __builtin_nontemporal_store(nv, dptr);
        }
      }
    }

    // enc = relu([prev | h] @ W_enc.T) via MFMA — waves 4..7, one 16x16 tile each
    // (also computes the mst enc-partial for its columns)
    if (w >= 4 && w < 8) {
      const int q = w - 4, mi = q >> 1, nj = q & 1;
      const int arow = mi * 16 + m16;
      const int col  = nj * 16 + m16;
      const int rb   = mi * 16 + ((lane >> 4) << 2);
      H8 ah = ld8(&hsrc[arow * SH + cp0]);
      const f32x4 zero = {0.f, 0.f, 0.f, 0.f};
      f32x4 acc = __builtin_amdgcn_mfma_f32_16x16x32_f16(ah.v, efW.v, zero, 0, 0, 0);
      float pr[4];
      #pragma unroll
      for (int r = 0; r < 4; ++r) {
        float ev = fmaxf(fmaf(w0col, sprev[rb + r], acc[r]), 0.f);
        ((f16*)senc16)[(rb + r) * (2 * SH) + col] = (f16)ev;
        pr[r] = wmstE * ev;
      }
      #pragma unroll
      for (int mask = 1; mask <= 8; mask <<= 1) {
        pr[0] += __shfl_xor(pr[0], mask);
        pr[1] += __shfl_xor(pr[1], mask);
        pr[2] += __shfl_xor(pr[2], mask);
        pr[3] += __shfl_xor(pr[3], mask);
      }
      if (m16 == 0) {
        #pragma unroll
        for (int r = 0; r < 4; ++r) smst_e[nj * 32 + rb + r] = pr[r];
      }
    }
    lds_barrier();   // B_enc: senc16 all rows visible to A/B MFMA waves

    // A/B = enc @ W_m1 halves via MFMA — waves 8..15, one 16x16 tile each
    if (w >= 8) {
      const int q = (w - 8) & 3, mi = q >> 1, nj = q & 1;
      const int arow = mi * 16 + m16;
      const int col  = nj * 16 + m16;
      const int rb   = mi * 16 + ((lane >> 4) << 2);
      H8 aE = ld8(&senc16[arow * SH + cp0]);
      const f32x4 zero = {0.f, 0.f, 0.f, 0.f};
      f32x4 acc = __builtin_amdgcn_mfma_f32_16x16x32_f16(aE.v, mfW.v, zero, 0, 0, 0);
      f16* dst = (w < 12) ? (f16*)sA16 : (f16*)sB16;
      #pragma unroll
      for (int r = 0; r < 4; ++r)
        dst[(rb + r) * (2 * SH) + col] = (f16)acc[r];
    }
    lds_barrier();   // B1: sA16/sB16 all rows visible

    // edge phase via MFMA (f16): wave w owns dst j0, j1
    {
      const f32x4 zero = {0.f, 0.f, 0.f, 0.f};
      #pragma unroll
      for (int jg = 0; jg < 2; ++jg) {
        const int j = jg ? j1 : j0;
        const h2 eaA = jg ? ea10 : ea00;
        const h2 eaB = jg ? ea11 : ea01;
        H8 aj = ld8(&sA16[j * SH + cp0]);
        H8 b0 = ld8(&sB16[m16 * SH + cp0]);
        H8 b1 = ld8(&sB16[(16 + m16) * SH + cp0]);
        F8 a0, a1;
        #pragma unroll
        for (int q = 0; q < 4; ++q) {
          h2 t0 = aj.e[q] + __builtin_elementwise_fma(eaA, wv16[q], b0.e[q]);
          h2 t1 = aj.e[q] + __builtin_elementwise_fma(eaB, wv16[q], b1.e[q]);
          a0.h[q] = __builtin_elementwise_max(t0, t0 * h001);   // pk lrelu
          a1.h[q] = __builtin_elementwise_max(t1, t1 * h001);
        }
        f32x4 d00 = __builtin_amdgcn_mfma_f32_16x16x32_f16(a0.v, bf0.v, zero, 0, 0, 0);
        f32x4 d01 = __builtin_amdgcn_mfma_f32_16x16x32_f16(a0.v, bf1.v, zero, 0, 0, 0);
        f32x4 d10 = __builtin_amdgcn_mfma_f32_16x16x32_f16(a1.v, bf0.v, zero, 0, 0, 0);
        f32x4 d11 = __builtin_amdgcn_mfma_f32_16x16x32_f16(a1.v, bf1.v, zero, 0, 0, 0);
        #pragma unroll
        for (int nt = 0; nt < 2; ++nt) {
          f32x4 da = nt ? d01 : d00;
          f32x4 db = nt ? d11 : d10;
          float mv = fmaxf(fmaxf(fmaxf(da[0], da[1]), fmaxf(da[2], da[3])),
                           fmaxf(fmaxf(db[0], db[1]), fmaxf(db[2], db[3])));
          mv = fmaxf(mv, __shfl_xor(mv, 16));
          mv = fmaxf(mv, __shfl_xor(mv, 32));
          if (lane < 16)
            ((f16*)saggr16)[j * (2 * SH) + nt * 16 + lane] = (f16)lrelu(mv);
        }
      }
    }
    lds_barrier();   // B_edge: saggr all rows visible to u-MFMA waves

    // u = lrelu([enc | aggr] @ W_u.T) via MFMA — waves 4..7, one 16x16 tile each
    if (w >= 4 && w < 8) {
      const int q = w - 4, mi = q >> 1, nj = q & 1;
      const int arow = mi * 16 + m16;
      const int col  = nj * 16 + m16;
      const int rb   = mi * 16 + ((lane >> 4) << 2);
      H8 aE = ld8(&senc16[arow * SH + cp0]);
      H8 aG = ld8(&saggr16[arow * SH + cp0]);
      const f32x4 zero = {0.f, 0.f, 0.f, 0.f};
      f32x4 acc = __builtin_amdgcn_mfma_f32_16x16x32_f16(aE.v, ufE.v, zero, 0, 0, 0);
      acc       = __builtin_amdgcn_mfma_f32_16x16x32_f16(aG.v, ufG.v, acc,  0, 0, 0);
      #pragma unroll
      for (int r = 0; r < 4; ++r)
        ((f16*)sA16)[(rb + r) * (2 * SH) + col] = (f16)lrelu(acc[r]);
    }
    lds_barrier();   // B_u: U (sA16) all rows visible to gate waves

    // GRU: waves 0..3 each own one 16x16 tile, all 6 gate GEMMs + hnew + mst h-part
    if (w < 4) {
      const int mi = w >> 1, nj = w & 1;
      const int arow = mi * 16 + m16;
      const int col  = nj * 16 + m16;
      const int rb   = mi * 16 + ((lane >> 4) << 2);
      H8 aU = ld8(&sA16[arow * SH + cp0]);
      H8 ah = ld8(&hsrc[arow * SH + cp0]);
      const f32x4 zero = {0.f, 0.f, 0.f, 0.f};
      f32x4 accR  = __builtin_amdgcn_mfma_f32_16x16x32_f16(aU.v, gfRi.v, zero, 0, 0, 0);
      accR        = __builtin_amdgcn_mfma_f32_16x16x32_f16(ah.v, gfRh.v, accR, 0, 0, 0);
      f32x4 accZ  = __builtin_amdgcn_mfma_f32_16x16x32_f16(aU.v, gfZi.v, zero, 0, 0, 0);
      accZ        = __builtin_amdgcn_mfma_f32_16x16x32_f16(ah.v, gfZh.v, accZ, 0, 0, 0);
      f32x4 accNi = __builtin_amdgcn_mfma_f32_16x16x32_f16(aU.v, gfNi.v, zero, 0, 0, 0);
      f32x4 accNh = __builtin_amdgcn_mfma_f32_16x16x32_f16(ah.v, gfNh.v, zero, 0, 0, 0);
      const float wmst_c = sWmst[32 + col];
      float pr[4];
      #pragma unroll
      for (int r = 0; r < 4; ++r) {
        float hold = (float)((const f16*)hsrc)[(rb + r) * (2 * SH) + col];
        float rg = fsigmoid(accR[r]);
        float zg = fsigmoid(accZ[r]);
        float nn = ftanh(accNi[r] + rg * accNh[r]);
        float hnew = (1.f - zg) * nn + zg * hold;
        ((f16*)hdst)[(rb + r) * (2 * SH) + col] = (f16)hnew;
        pr[r] = hnew * wmst_c;
      }
      #pragma unroll
      for (int mask = 1; mask <= 8; mask <<= 1) {
        pr[0] += __shfl_xor(pr[0], mask);
        pr[1] += __shfl_xor(pr[1], mask);
        pr[2] += __shfl_xor(pr[2], mask);
        pr[3] += __shfl_xor(pr[3], mask);
      }
      if (m16 == 0) {
        #pragma unroll
        for (int r = 0; r < 4; ++r) smst_h[nj * 32 + rb + r] = pr[r];
      }
    }
    lds_barrier();   // B2: hdst + smst_e + smst_h visible

    // masked argmax — waves 4..7 only (sole consumers of prev/sprev)
    if (w >= 4 && w < 8) {
      float sc = smst_e[l32] + smst_e[32 + l32] + smst_h[l32] + smst_h[32 + l32];
      float val = (prev_lane > 0.f) ? NEGV : sc;
      uint32_t u = __float_as_uint(val);
      u = (u & 0x80000000u) ? ~u : (u | 0x80000000u);   // monotone f32->u32
      uint32_t key = (u & 0xFFFFFFE0u) | (uint32_t)(31 - l32);
      #pragma unroll
      for (int mask = 16; mask >= 1; mask >>= 1) {
        uint32_t o = (uint32_t)__shfl_xor((int)key, mask);
        key = key > o ? key : o;
      }
      int idx = 31 - (int)(key & 31u);
      if (l32 == idx) {
        prev_lane = 1.0f;
        sprev[idx] = 1.0f;   // 4 redundant same-value writes: benign; own-wave visible next step
      }
    }
  }

  // ---- final predictor ---- (h lives in sha after 32 steps)
  {
    const f16* hrow = (const f16*)&sha[p * SH];
    float c1 = 0.f, c2 = 0.f;
    #pragma unroll
    for (int c = 0; c < 32; ++c) {
      float hc = (float)hrow[c];
      c1 = fmaf(W_p1[k * 65 + c],      hc, c1);
      c2 = fmaf(W_p1[k * 65 + 32 + c], hc, c2);
    }
    sC1[p * S3 + k] = c1;
    sC2[p * S3 + k] = c2;
  }
  lds_barrier();

  // out(src=i, dst=j): i = p, j = k
  {
    const int i = p, j = k;
    float eat = sea[j * S3 + i];
    float acc = 0.f;
    #pragma unroll
    for (int c = 0; c < 32; ++c) {
      float v = sC1[i * S3 + c] + sC2[j * S3 + c] + eat * swp1e[c];
      acc = fmaf(W_p2[c], fmaxf(v, 0.f), acc);
    }
    out[(size_t)(g * NL + i) * NTOT + (g * NL + j)] = acc;
  }
}

extern "C" void kernel_launch(void* const* d_in, const int* in_sizes, int n_in,
                              void* d_out, int out_size, void* d_ws, size_t ws_size,
                              hipStream_t stream) {
  const float* x         = (const float*)d_in[0];
  const float* edge_attr = (const float*)d_in[1];
  const float* W_enc     = (const float*)d_in[2];
  const float* W_m1      = (const float*)d_in[3];
  const float* W_m2      = (const float*)d_in[4];
  const float* W_u       = (const float*)d_in[5];
  const float* W_ih      = (const float*)d_in[6];
  const float* W_hh      = (const float*)d_in[7];
  const float* W_mst     = (const float*)d_in[8];
  const float* W_p1      = (const float*)d_in[9];
  const float* W_p2      = (const float*)d_in[10];
  float* out = (float*)d_out;

  hipLaunchKernelGGL(prims_fused, dim3(NG), dim3(NT), 0, stream,
                     x, edge_attr, W_enc, W_m1, W_m2, W_u, W_ih, W_hh,
                     W_mst, W_p1, W_p2, out);
}

// Round 27
// 121.625 us; speedup vs baseline: 1.0834x; 1.0834x over previous
//
#include <hip/hip_runtime.h>
#include <stdint.h>
#include <math.h>

#define NEGV -1000000000.0f

constexpr int NG   = 256;   // graphs
constexpr int NL   = 32;    // nodes per graph == L == steps
constexpr int NT   = 1024;  // threads per block
constexpr int NTOT = 8192;  // total nodes
constexpr int S3   = 33;    // f32 stride for per-lane-row arrays
constexpr int SH   = 20;    // h2 stride (40 f16, 80B rows, 16B-aligned)

typedef _Float16 f16;
typedef __attribute__((ext_vector_type(2))) _Float16 h2;
typedef __attribute__((ext_vector_type(8))) _Float16 h8;
typedef __attribute__((ext_vector_type(8))) _Float16 f16x8;
typedef __attribute__((ext_vector_type(4))) float f32x4;

union H8 { h8 v; h2 e[4]; };

__device__ __forceinline__ h2 mkh2(float a, float b) {   // RNE pack
  return (h2){(_Float16)a, (_Float16)b};
}

__device__ __forceinline__ H8 ld8(const h2* p) {
  H8 r; r.v = *(const h8*)__builtin_assume_aligned(p, 16); return r;
}

__device__ __forceinline__ float lrelu(float v) { return fmaxf(v, 0.01f * v); }

__device__ __forceinline__ void lds_barrier() {
  asm volatile("s_waitcnt lgkmcnt(0)" ::: "memory");
  __builtin_amdgcn_sched_barrier(0);
  __builtin_amdgcn_s_barrier();
  __builtin_amdgcn_sched_barrier(0);
}

__device__ __forceinline__ float fsigmoid(float x) {
  return __builtin_amdgcn_rcpf(1.f + __expf(-x));
}
__device__ __forceinline__ float ftanh(float x) {
  x = fminf(fmaxf(x, -15.f), 15.f);
  float e = __expf(2.f * x);
  return (e - 1.f) * __builtin_amdgcn_rcpf(e + 1.f);
}

union F8 { h2 h[4]; f16x8 v; };

// load 8 consecutive f32 of row `row` of a 32-wide matrix as one f16 fragment
__device__ __forceinline__ void loadWrow(const float* __restrict__ W, int row, int kslc, F8& f) {
  const float4 lo = *(const float4*)&W[row * 32 + kslc];
  const float4 hi = *(const float4*)&W[row * 32 + kslc + 4];
  f.h[0] = mkh2(lo.x, lo.y); f.h[1] = mkh2(lo.z, lo.w);
  f.h[2] = mkh2(hi.x, hi.y); f.h[3] = mkh2(hi.z, hi.w);
}
// same for a 64-wide matrix (W_u)
__device__ __forceinline__ void loadWrow64(const float* __restrict__ W, int row, int kslc, F8& f) {
  const float4 lo = *(const float4*)&W[row * 64 + kslc];
  const float4 hi = *(const float4*)&W[row * 64 + kslc + 4];
  f.h[0] = mkh2(lo.x, lo.y); f.h[1] = mkh2(lo.z, lo.w);
  f.h[2] = mkh2(hi.x, hi.y); f.h[3] = mkh2(hi.z, hi.w);
}
// arbitrary-stride matrix — rows not 16B-aligned, scalar loads (init-only)
__device__ __forceinline__ void loadWrowS(const float* __restrict__ W, int row, int stride, int col0, F8& f) {
  #pragma unroll
  for (int q = 0; q < 4; ++q)
    f.h[q] = mkh2(W[row * stride + col0 + 2 * q], W[row * stride + col0 + 2 * q + 1]);
}

__global__ __launch_bounds__(NT, 4) void prims_fused(
    const float* __restrict__ x, const float* __restrict__ edge_attr,
    const float* __restrict__ W_enc, const float* __restrict__ W_m1,
    const float* __restrict__ W_m2, const float* __restrict__ W_u,
    const float* __restrict__ W_ih, const float* __restrict__ W_hh,
    const float* __restrict__ W_mst, const float* __restrict__ W_p1,
    const float* __restrict__ W_p2, float* __restrict__ out)
{
  // ping-pong hidden state (f16, stride SH=20 h2)
  __shared__ __align__(16) h2 sha[NL * SH];
  __shared__ __align__(16) h2 shb[NL * SH];
  __shared__ __align__(16) h2 senc16[NL * SH];   // enc
  __shared__ __align__(16) h2 sA16[NL * SH];     // msg dst-part; then u
  __shared__ __align__(16) h2 sB16[NL * SH];     // msg src-part
  __shared__ __align__(16) h2 saggr16[NL * SH];  // segment max
  __shared__ h2 swea16[16];                      // W_m1[:,64] pairs
  // f32 oddments
  __shared__ float sea[NL * S3];   // sea[j*S3 + i] = ea(src i, dst j)
  __shared__ float smst_e[2 * NL]; // mst enc-part per (nj, row)
  __shared__ float smst_h[2 * NL]; // mst h-part per (nj, row)
  __shared__ float sprev[NL];      // prev vector (for enc-MFMA correction)
  __shared__ float sWmst[2 * NL];
  __shared__ float swp1e[NL];      // W_p1[:,64]
  __shared__ float sC1[NL * S3];   // final predictor src-part
  __shared__ float sC2[NL * S3];   // final predictor dst-part

  const int t    = threadIdx.x;
  const int g    = blockIdx.x;
  const int p    = t >> 5;   // node row
  const int k    = t & 31;   // feature col
  const int w    = t >> 6;   // wave id (16)
  const int lane = t & 63;
  const int l32  = lane & 31;
  const int m16  = lane & 15;
  const int c0   = (lane >> 4) * 8;   // MFMA k-chunk base (f16 elems)
  const int cp0  = (lane >> 4) * 4;   // same in half2 units

  // ---- W_m2^T B-fragments (f16, resident in registers) ----
  F8 bf0, bf1;
  #pragma unroll
  for (int q = 0; q < 4; ++q) {
    bf0.h[q] = mkh2(W_m2[m16 * 32 + c0 + 2 * q],        W_m2[m16 * 32 + c0 + 2 * q + 1]);
    bf1.h[q] = mkh2(W_m2[(16 + m16) * 32 + c0 + 2 * q], W_m2[(16 + m16) * 32 + c0 + 2 * q + 1]);
  }

  // ---- per-wave GRU gate B-fragments (waves 0..3: one 16x16 tile, all 6 GEMMs) ----
  F8 gfRi, gfRh, gfZi, gfZh, gfNi, gfNh;
  if (w < 4) {
    const int nj = w & 1;
    const int wrow = nj * 16 + m16;   // weight row = output feature
    loadWrow(W_ih, wrow,      c0, gfRi); loadWrow(W_hh, wrow,      c0, gfRh);
    loadWrow(W_ih, 32 + wrow, c0, gfZi); loadWrow(W_hh, 32 + wrow, c0, gfZh);
    loadWrow(W_ih, 64 + wrow, c0, gfNi); loadWrow(W_hh, 64 + wrow, c0, gfNh);
  }

  // ---- per-wave u-phase + enc-phase B-fragments (waves 4..7) ----
  F8 ufE, ufG, efW;
  float w0col = 0.f, wmstE = 0.f;
  if (w >= 4 && w < 8) {
    const int q = w - 4;
    const int nj = q & 1;
    const int wrow = nj * 16 + m16;
    loadWrow64(W_u, wrow, c0,      ufE);        // K-cols  0..31 (enc part)
    loadWrow64(W_u, wrow, 32 + c0, ufG);        // K-cols 32..63 (aggr part)
    loadWrowS(W_enc, wrow, 33, 1 + c0, efW);    // W_enc[:,1:33] rows
    w0col = W_enc[wrow * 33];                   // W_enc[:,0] (prev term)
    wmstE = W_mst[wrow];                        // mst enc coefficient
  }

  // ---- per-wave A/B-phase B-fragments (waves 8..15: one 16x16 tile each) ----
  F8 mfW;   // W_m1 rows, cols 0..31 (A) or 32..63 (B)
  if (w >= 8) {
    const int q = (w - 8) & 3;
    const int nj = q & 1;
    const int wrow = nj * 16 + m16;
    const int colbase = (w < 12) ? 0 : 32;
    loadWrowS(W_m1, wrow, 65, colbase + c0, mfW);
  }

  // ---- one-time staging ----
  if (t < 16) swea16[t] = mkh2(W_m1[(2 * t) * 65 + 64], W_m1[(2 * t + 1) * 65 + 64]);
  if (t < NL) { swp1e[t] = W_p1[t * 65 + 64]; sprev[t] = x[(size_t)(g * NL + t) * 32]; }
  if (t < 2 * NL) sWmst[t] = W_mst[t];
  {
    int i = t >> 5, j = t & 31;           // edge t = i*32+j (src i, dst j)
    sea[j * S3 + i] = edge_attr[g * 1024 + t];
  }
  for (int idx = t; idx < NL * SH; idx += NT) sha[idx] = (h2){(_Float16)0.f, (_Float16)0.f};

  float prev_lane = x[(size_t)(g * NL + l32) * 32];  // prev[l32], for argmax (waves 4..7)

  __syncthreads();

  // hoisted static edge-phase operands
  h2 wv16[4];
  #pragma unroll
  for (int q = 0; q < 4; ++q) wv16[q] = swea16[cp0 + q];
  const int j0 = 2 * w, j1 = 2 * w + 1;
  h2 ea00, ea01, ea10, ea11;
  {
    f16 e;
    e = (f16)sea[j0 * S3 + m16];      ea00 = (h2){e, e};
    e = (f16)sea[j0 * S3 + 16 + m16]; ea01 = (h2){e, e};
    e = (f16)sea[j1 * S3 + m16];      ea10 = (h2){e, e};
    e = (f16)sea[j1 * S3 + 16 + m16]; ea11 = (h2){e, e};
  }
  const h2 h001 = {(_Float16)0.01f, (_Float16)0.01f};

  // ---- 32 steps ----
  for (int s = 0; s < 32; ++s) {
    h2* hsrc = (s & 1) ? shb : sha;
    h2* hdst = (s & 1) ? sha : shb;

    // NEG-fill slice of this graph's band (all 16 waves, 2 float4 each; skips diag block)
    {
      const f32x4 nv = {NEGV, NEGV, NEGV, NEGV};
      #pragma unroll
      for (int q = 0; q < 2; ++q) {
        int idx = (s * 2 + q) * NT + t;
        int row = idx >> 11;
        int c4  = idx & 2047;
        if ((c4 >> 3) != g) {
          f32x4* dptr = reinterpret_cast<f32x4*>(out + (size_t)(g * NL + row) * NTOT) + c4;
          __builtin_nontemporal_store(nv, dptr);
        }
      }
    }

    // enc = relu([prev | h] @ W_enc.T) via MFMA — waves 4..7, one 16x16 tile each
    // (also computes the mst enc-partial for its columns)
    if (w >= 4 && w < 8) {
      const int q = w - 4, mi = q >> 1, nj = q & 1;
      const int arow = mi * 16 + m16;
      const int col  = nj * 16 + m16;
      const int rb   = mi * 16 + ((lane >> 4) << 2);
      H8 ah = ld8(&hsrc[arow * SH + cp0]);
      const f32x4 zero = {0.f, 0.f, 0.f, 0.f};
      f32x4 acc = __builtin_amdgcn_mfma_f32_16x16x32_f16(ah.v, efW.v, zero, 0, 0, 0);
      float pr[4];
      #pragma unroll
      for (int r = 0; r < 4; ++r) {
        float ev = fmaxf(fmaf(w0col, sprev[rb + r], acc[r]), 0.f);
        ((f16*)senc16)[(rb + r) * (2 * SH) + col] = (f16)ev;
        pr[r] = wmstE * ev;
      }
      #pragma unroll
      for (int mask = 1; mask <= 8; mask <<= 1) {
        pr[0] += __shfl_xor(pr[0], mask);
        pr[1] += __shfl_xor(pr[1], mask);
        pr[2] += __shfl_xor(pr[2], mask);
        pr[3] += __shfl_xor(pr[3], mask);
      }
      if (m16 == 0) {
        #pragma unroll
        for (int r = 0; r < 4; ++r) smst_e[nj * 32 + rb + r] = pr[r];
      }
    }
    lds_barrier();   // B_enc: senc16 all rows visible to A/B MFMA waves

    // A/B = enc @ W_m1 halves via MFMA — waves 8..15, one 16x16 tile each
    if (w >= 8) {
      const int q = (w - 8) & 3, mi = q >> 1, nj = q & 1;
      const int arow = mi * 16 + m16;
      const int col  = nj * 16 + m16;
      const int rb   = mi * 16 + ((lane >> 4) << 2);
      H8 aE = ld8(&senc16[arow * SH + cp0]);
      const f32x4 zero = {0.f, 0.f, 0.f, 0.f};
      f32x4 acc = __builtin_amdgcn_mfma_f32_16x16x32_f16(aE.v, mfW.v, zero, 0, 0, 0);
      f16* dst = (w < 12) ? (f16*)sA16 : (f16*)sB16;
      #pragma unroll
      for (int r = 0; r < 4; ++r)
        dst[(rb + r) * (2 * SH) + col] = (f16)acc[r];
    }
    lds_barrier();   // B1: sA16/sB16 all rows visible

    // edge phase via MFMA (f16): wave w owns dst j0, j1
    {
      const f32x4 zero = {0.f, 0.f, 0.f, 0.f};
      #pragma unroll
      for (int jg = 0; jg < 2; ++jg) {
        const int j = jg ? j1 : j0;
        const h2 eaA = jg ? ea10 : ea00;
        const h2 eaB = jg ? ea11 : ea01;
        H8 aj = ld8(&sA16[j * SH + cp0]);
        H8 b0 = ld8(&sB16[m16 * SH + cp0]);
        H8 b1 = ld8(&sB16[(16 + m16) * SH + cp0]);
        F8 a0, a1;
        #pragma unroll
        for (int q = 0; q < 4; ++q) {
          h2 t0 = aj.e[q] + __builtin_elementwise_fma(eaA, wv16[q], b0.e[q]);
          h2 t1 = aj.e[q] + __builtin_elementwise_fma(eaB, wv16[q], b1.e[q]);
          a0.h[q] = __builtin_elementwise_max(t0, t0 * h001);   // pk lrelu
          a1.h[q] = __builtin_elementwise_max(t1, t1 * h001);
        }
        f32x4 d00 = __builtin_amdgcn_mfma_f32_16x16x32_f16(a0.v, bf0.v, zero, 0, 0, 0);
        f32x4 d01 = __builtin_amdgcn_mfma_f32_16x16x32_f16(a0.v, bf1.v, zero, 0, 0, 0);
        f32x4 d10 = __builtin_amdgcn_mfma_f32_16x16x32_f16(a1.v, bf0.v, zero, 0, 0, 0);
        f32x4 d11 = __builtin_amdgcn_mfma_f32_16x16x32_f16(a1.v, bf1.v, zero, 0, 0, 0);
        #pragma unroll
        for (int nt = 0; nt < 2; ++nt) {
          f32x4 da = nt ? d01 : d00;
          f32x4 db = nt ? d11 : d10;
          float mv = fmaxf(fmaxf(fmaxf(da[0], da[1]), fmaxf(da[2], da[3])),
                           fmaxf(fmaxf(db[0], db[1]), fmaxf(db[2], db[3])));
          mv = fmaxf(mv, __shfl_xor(mv, 16));
          mv = fmaxf(mv, __shfl_xor(mv, 32));
          if (lane < 16)
            ((f16*)saggr16)[j * (2 * SH) + nt * 16 + lane] = (f16)lrelu(mv);
        }
      }
    }
    lds_barrier();   // B_edge: saggr all rows visible to u-MFMA waves

    // u = lrelu([enc | aggr] @ W_u.T) via MFMA — waves 4..7, one 16x16 tile each
    if (w >= 4 && w < 8) {
      const int q = w - 4, mi = q >> 1, nj = q & 1;
      const int arow = mi * 16 + m16;
      const int col  = nj * 16 + m16;
      const int rb   = mi * 16 + ((lane >> 4) << 2);
      H8 aE = ld8(&senc16[arow * SH + cp0]);
      H8 aG = ld8(&saggr16[arow * SH + cp0]);
      const f32x4 zero = {0.f, 0.f, 0.f, 0.f};
      f32x4 acc = __builtin_amdgcn_mfma_f32_16x16x32_f16(aE.v, ufE.v, zero, 0, 0, 0);
      acc       = __builtin_amdgcn_mfma_f32_16x16x32_f16(aG.v, ufG.v, acc,  0, 0, 0);
      #pragma unroll
      for (int r = 0; r < 4; ++r)
        ((f16*)sA16)[(rb + r) * (2 * SH) + col] = (f16)lrelu(acc[r]);
    }
    lds_barrier();   // B_u: U (sA16) all rows visible to gate waves

    // GRU: waves 0..3 each own one 16x16 tile, all 6 gate GEMMs + hnew + mst h-part
    if (w < 4) {
      const int mi = w >> 1, nj = w & 1;
      const int arow = mi * 16 + m16;
      const int col  = nj * 16 + m16;
      const int rb   = mi * 16 + ((lane >> 4) << 2);
      H8 aU = ld8(&sA16[arow * SH + cp0]);
      H8 ah = ld8(&hsrc[arow * SH + cp0]);
      const f32x4 zero = {0.f, 0.f, 0.f, 0.f};
      f32x4 accR  = __builtin_amdgcn_mfma_f32_16x16x32_f16(aU.v, gfRi.v, zero, 0, 0, 0);
      accR        = __builtin_amdgcn_mfma_f32_16x16x32_f16(ah.v, gfRh.v, accR, 0, 0, 0);
      f32x4 accZ  = __builtin_amdgcn_mfma_f32_16x16x32_f16(aU.v, gfZi.v, zero, 0, 0, 0);
      accZ        = __builtin_amdgcn_mfma_f32_16x16x32_f16(ah.v, gfZh.v, accZ, 0, 0, 0);
      f32x4 accNi = __builtin_amdgcn_mfma_f32_16x16x32_f16(aU.v, gfNi.v, zero, 0, 0, 0);
      f32x4 accNh = __builtin_amdgcn_mfma_f32_16x16x32_f16(ah.v, gfNh.v, zero, 0, 0, 0);
      const float wmst_c = sWmst[32 + col];
      float pr[4];
      #pragma unroll
      for (int r = 0; r < 4; ++r) {
        float hold = (float)((const f16*)hsrc)[(rb + r) * (2 * SH) + col];
        float rg = fsigmoid(accR[r]);
        float zg = fsigmoid(accZ[r]);
        float nn = ftanh(accNi[r] + rg * accNh[r]);
        float hnew = (1.f - zg) * nn + zg * hold;
        ((f16*)hdst)[(rb + r) * (2 * SH) + col] = (f16)hnew;
        pr[r] = hnew * wmst_c;
      }
      #pragma unroll
      for (int mask = 1; mask <= 8; mask <<= 1) {
        pr[0] += __shfl_xor(pr[0], mask);
        pr[1] += __shfl_xor(pr[1], mask);
        pr[2] += __shfl_xor(pr[2], mask);
        pr[3] += __shfl_xor(pr[3], mask);
      }
      if (m16 == 0) {
        #pragma unroll
        for (int r = 0; r < 4; ++r) smst_h[nj * 32 + rb + r] = pr[r];
      }
    }
    lds_barrier();   // B2: hdst + smst_e + smst_h visible

    // masked argmax — waves 4..7 only (sole consumers of prev/sprev)
    if (w >= 4 && w < 8) {
      float sc = smst_e[l32] + smst_e[32 + l32] + smst_h[l32] + smst_h[32 + l32];
      float val = (prev_lane > 0.f) ? NEGV : sc;
      uint32_t u = __float_as_uint(val);
      u = (u & 0x80000000u) ? ~u : (u | 0x80000000u);   // monotone f32->u32
      uint32_t key = (u & 0xFFFFFFE0u) | (uint32_t)(31 - l32);
      #pragma unroll
      for (int mask = 16; mask >= 1; mask >>= 1) {
        uint32_t o = (uint32_t)__shfl_xor((int)key, mask);
        key = key > o ? key : o;
      }
      int idx = 31 - (int)(key & 31u);
      if (l32 == idx) {
        prev_lane = 1.0f;
        sprev[idx] = 1.0f;   // 4 redundant same-value writes: benign; own-wave visible next step
      }
    }
  }

  // ---- final predictor ---- (h lives in sha after 32 steps)
  {
    const f16* hrow = (const f16*)&sha[p * SH];
    float c1 = 0.f, c2 = 0.f;
    #pragma unroll
    for (int c = 0; c < 32; ++c) {
      float hc = (float)hrow[c];
      c1 = fmaf(W_p1[k * 65 + c],      hc, c1);
      c2 = fmaf(W_p1[k * 65 + 32 + c], hc, c2);
    }
    sC1[p * S3 + k] = c1;
    sC2[p * S3 + k] = c2;
  }
  lds_barrier();

  // out(src=i, dst=j): i = p, j = k
  {
    const int i = p, j = k;
    float eat = sea[j * S3 + i];
    float acc = 0.f;
    #pragma unroll
    for (int c = 0; c < 32; ++c) {
      float v = sC1[i * S3 + c] + sC2[j * S3 + c] + eat * swp1e[c];
      acc = fmaf(W_p2[c], fmaxf(v, 0.f), acc);
    }
    out[(size_t)(g * NL + i) * NTOT + (g * NL + j)] = acc;
  }
}

extern "C" void kernel_launch(void* const* d_in, const int* in_sizes, int n_in,
                              void* d_out, int out_size, void* d_ws, size_t ws_size,
                              hipStream_t stream) {
  const float* x         = (const float*)d_in[0];
  const float* edge_attr = (const float*)d_in[1];
  const float* W_enc     = (const float*)d_in[2];
  const float* W_m1      = (const float*)d_in[3];
  const float* W_m2      = (const float*)d_in[4];
  const float* W_u       = (const float*)d_in[5];
  const float* W_ih      = (const float*)d_in[6];
  const float* W_hh      = (const float*)d_in[7];
  const float* W_mst     = (const float*)d_in[8];
  const float* W_p1      = (const float*)d_in[9];
  const float* W_p2      = (const float*)d_in[10];
  float* out = (float*)d_out;

  hipLaunchKernelGGL(prims_fused, dim3(NG), dim3(NT), 0, stream,
                     x, edge_attr, W_enc, W_m1, W_m2, W_u, W_ih, W_hh,
                     W_mst, W_p1, W_p2, out);
}